// Round 1
// baseline (686.851 us; speedup 1.0000x reference)
//
#include <hip/hip_runtime.h>
#include <hip/hip_bf16.h>

typedef __hip_bfloat16 bf16;
typedef float f32x4 __attribute__((ext_vector_type(4)));
typedef short bf16x8 __attribute__((ext_vector_type(8)));

static __device__ __forceinline__ void gload_lds16(const void* g, void* l) {
    __builtin_amdgcn_global_load_lds(
        (const __attribute__((address_space(1))) void*)g,
        (__attribute__((address_space(3))) void*)l, 16, 0, 0);
}

// ---------------- fp32 -> bf16 conversion (vectorized) ----------------
__global__ __launch_bounds__(256) void cvt_x_kernel(const float4* __restrict__ x,
                                                    bf16* __restrict__ xb, int n4) {
    int i = blockIdx.x * 256 + threadIdx.x;
    const int stride = gridDim.x * 256;
    for (; i < n4; i += stride) {
        float4 v = x[i];
        alignas(8) bf16 tmp[4];
        tmp[0] = __float2bfloat16(v.x);
        tmp[1] = __float2bfloat16(v.y);
        tmp[2] = __float2bfloat16(v.z);
        tmp[3] = __float2bfloat16(v.w);
        *reinterpret_cast<uint2*>(xb + 4l * i) = *reinterpret_cast<uint2*>(tmp);
    }
}

// ---------------- build W_eff^T (fold LoRA), bf16 ----------------
// wt[n][k] = qkv_w[k][n] + (n<384 ? qa@qb : 0) + (n>=768 ? va@vb : 0)
__global__ __launch_bounds__(256) void build_wefft_kernel(
    const float* __restrict__ qkv_w, const float* __restrict__ qa,
    const float* __restrict__ qb, const float* __restrict__ va,
    const float* __restrict__ vb, bf16* __restrict__ wt) {
    int idx = blockIdx.x * 256 + threadIdx.x;  // 1152*384 total
    int ncol = idx / 384;
    int k = idx - ncol * 384;
    float v = qkv_w[k * 1152 + ncol];
    if (ncol < 384) {
        float s = 0.f;
#pragma unroll
        for (int j = 0; j < 16; ++j) s += qa[k * 16 + j] * qb[j * 384 + ncol];
        v += s;
    } else if (ncol >= 768) {
        int nc = ncol - 768;
        float s = 0.f;
#pragma unroll
        for (int j = 0; j < 16; ++j) s += va[k * 16 + j] * vb[j * 384 + nc];
        v += s;
    }
    wt[(long)ncol * 384 + k] = __float2bfloat16(v);
}

// ---------------- transpose proj_w, bf16 ----------------
__global__ __launch_bounds__(256) void build_projt_kernel(const float* __restrict__ pw,
                                                          bf16* __restrict__ pt) {
    int idx = blockIdx.x * 256 + threadIdx.x;  // 384*384 total
    int ncol = idx / 384;
    int k = idx - ncol * 384;
    pt[(long)ncol * 384 + k] = __float2bfloat16(pw[k * 384 + ncol]);
}

// ---------------- bf16 GEMM: C[M,N] = A[M,K] @ BT[N,K]^T + bias ----------------
// 128x128 tile, BK=32, 4 waves each computing 64x64 via 4x4 frags of 16x16x32 MFMA.
template <bool OUT_BF16>
__global__ __launch_bounds__(256) void gemm_kernel(const bf16* __restrict__ A,
                                                   const bf16* __restrict__ BT,
                                                   const float* __restrict__ bias,
                                                   void* __restrict__ Cout, int N, int K) {
    __shared__ short Al[128 * 32];
    __shared__ short Bl[128 * 32];
    const int t = threadIdx.x;
    const int lane = t & 63;
    const int wave = t >> 6;
    const int wr = wave >> 1;  // 0..1
    const int wc = wave & 1;   // 0..1
    const long rowBase = (long)blockIdx.y * 128;
    const long colBase = (long)blockIdx.x * 128;

    f32x4 acc[4][4];
#pragma unroll
    for (int m = 0; m < 4; ++m)
#pragma unroll
        for (int n = 0; n < 4; ++n) acc[m][n] = (f32x4){0.f, 0.f, 0.f, 0.f};

    const int r0 = t >> 2;         // staging row (0..63)
    const int kc0 = (t & 3) * 8;   // staging k offset

    for (int k0 = 0; k0 < K; k0 += 32) {
        __syncthreads();  // previous iteration's ds_reads are complete in all waves
        gload_lds16(A + (rowBase + r0) * K + k0 + kc0, &Al[t * 8]);
        gload_lds16(A + (rowBase + r0 + 64) * K + k0 + kc0, &Al[(t + 256) * 8]);
        gload_lds16(BT + (colBase + r0) * K + k0 + kc0, &Bl[t * 8]);
        gload_lds16(BT + (colBase + r0 + 64) * K + k0 + kc0, &Bl[(t + 256) * 8]);
        asm volatile("s_waitcnt vmcnt(0)" ::: "memory");
        __syncthreads();

        bf16x8 af[4], bfr[4];
        const int rsel = (lane >> 4) * 8;  // k slice within row
#pragma unroll
        for (int m = 0; m < 4; ++m)
            af[m] = *(const bf16x8*)&Al[(wr * 64 + m * 16 + (lane & 15)) * 32 + rsel];
#pragma unroll
        for (int n = 0; n < 4; ++n)
            bfr[n] = *(const bf16x8*)&Bl[(wc * 64 + n * 16 + (lane & 15)) * 32 + rsel];
#pragma unroll
        for (int m = 0; m < 4; ++m)
#pragma unroll
            for (int n = 0; n < 4; ++n)
                acc[m][n] = __builtin_amdgcn_mfma_f32_16x16x32_bf16(af[m], bfr[n],
                                                                    acc[m][n], 0, 0, 0);
    }

    // epilogue: C/D layout col=lane&15, row=(lane>>4)*4+reg  [m89/m91 verified]
    const int crow0 = wr * 64 + (lane >> 4) * 4;
    const long ccol0 = colBase + wc * 64 + (lane & 15);
#pragma unroll
    for (int m = 0; m < 4; ++m) {
#pragma unroll
        for (int n = 0; n < 4; ++n) {
            const long col = ccol0 + n * 16;
            const float bv = bias[col];
#pragma unroll
            for (int r = 0; r < 4; ++r) {
                const long row = rowBase + crow0 + m * 16 + r;
                float v = acc[m][n][r] + bv;
                if (OUT_BF16)
                    ((bf16*)Cout)[row * N + col] = __float2bfloat16(v);
                else
                    ((float*)Cout)[row * N + col] = v;
            }
        }
    }
}

// ---------------- window attention: one block per (b, h) ----------------
__global__ __launch_bounds__(256) void attn_kernel(const bf16* __restrict__ qkv,
                                                   const float* __restrict__ mask,
                                                   const float* __restrict__ rpb,
                                                   bf16* __restrict__ out) {
    const int bh = blockIdx.x;
    const int b = bh / 12;
    const int h = bh - b * 12;
    __shared__ float qs[49 * 32];
    __shared__ float ks[49 * 33];  // padded: avoids same-bank column reads in S loop
    __shared__ float vs[49 * 32];
    __shared__ float S[49 * 50];
    const int t = threadIdx.x;
    const size_t rowbase = (size_t)b * 49 * 1152;

    for (int idx = t; idx < 49 * 32; idx += 256) {
        int n = idx >> 5, d = idx & 31;
        size_t g = rowbase + (size_t)n * 1152 + h * 32 + d;
        qs[idx] = __bfloat162float(qkv[g]);
        ks[n * 33 + d] = __bfloat162float(qkv[g + 384]);
        vs[idx] = __bfloat162float(qkv[g + 768]);
    }
    __syncthreads();

    const float scale = 0.17677669529663687f;  // 32^-0.5
    const int w = b & 63;
    for (int idx = t; idx < 49 * 49; idx += 256) {
        int i = idx / 49, j = idx - i * 49;
        float acc = 0.f;
#pragma unroll
        for (int d = 0; d < 32; ++d) acc += qs[i * 32 + d] * ks[j * 33 + d];
        int yi = i / 7, xi = i - yi * 7;
        int yj = j / 7, xj = j - yj * 7;
        int rel = (yi - yj + 6) * 13 + (xi - xj + 6);
        S[i * 50 + j] = acc * scale + rpb[rel * 12 + h] + mask[w * 2401 + idx];
    }
    __syncthreads();

    if (t < 49) {
        float m = -1e30f;
        for (int j = 0; j < 49; ++j) m = fmaxf(m, S[t * 50 + j]);
        float sum = 0.f;
        for (int j = 0; j < 49; ++j) {
            float e = __expf(S[t * 50 + j] - m);
            S[t * 50 + j] = e;
            sum += e;
        }
        float inv = 1.f / sum;
        for (int j = 0; j < 49; ++j) S[t * 50 + j] *= inv;
    }
    __syncthreads();

    for (int idx = t; idx < 49 * 32; idx += 256) {
        int n = idx >> 5, d = idx & 31;
        float acc = 0.f;
        for (int j = 0; j < 49; ++j) acc += S[n * 50 + j] * vs[j * 32 + d];
        out[(size_t)(b * 49 + n) * 384 + h * 32 + d] = __float2bfloat16(acc);
    }
}

extern "C" void kernel_launch(void* const* d_in, const int* in_sizes, int n_in,
                              void* d_out, int out_size, void* d_ws, size_t ws_size,
                              hipStream_t stream) {
    (void)in_sizes; (void)n_in; (void)out_size; (void)ws_size;
    const float* x      = (const float*)d_in[0];
    const float* mask   = (const float*)d_in[1];
    const float* qkv_w  = (const float*)d_in[2];
    const float* qkv_b  = (const float*)d_in[3];
    const float* qa_w   = (const float*)d_in[4];
    const float* qb_w   = (const float*)d_in[5];
    const float* va_w   = (const float*)d_in[6];
    const float* vb_w   = (const float*)d_in[7];
    const float* rpb    = (const float*)d_in[8];
    const float* proj_w = (const float*)d_in[9];
    const float* proj_b = (const float*)d_in[10];

    char* ws = (char*)d_ws;
    bf16* xb    = (bf16*)(ws);                    // 77,070,336 B
    bf16* wefft = (bf16*)(ws + 77070336);         //    884,736 B
    bf16* projt = (bf16*)(ws + 77955072);         //    294,912 B
    bf16* qkv   = (bf16*)(ws + 78249984);         // 231,211,008 B
    bf16* attno = (bf16*)(ws + 309460992);        // 77,070,336 B  (total ~368.6 MB)

    cvt_x_kernel<<<2048, 256, 0, stream>>>((const float4*)x, xb, 9633792);
    build_wefft_kernel<<<1728, 256, 0, stream>>>(qkv_w, qa_w, qb_w, va_w, vb_w, wefft);
    build_projt_kernel<<<576, 256, 0, stream>>>(proj_w, projt);
    // qkv[100352,1152] = xb[100352,384] @ wefft^T + qkv_b
    gemm_kernel<true><<<dim3(9, 784), 256, 0, stream>>>(xb, wefft, qkv_b, qkv, 1152, 384);
    attn_kernel<<<24576, 256, 0, stream>>>(qkv, mask, rpb, attno);
    // out[100352,384] = attno @ projt^T + proj_b  (fp32)
    gemm_kernel<false><<<dim3(3, 784), 256, 0, stream>>>(attno, projt, proj_b, d_out, 384, 384);
}

// Round 3
// 432.439 us; speedup vs baseline: 1.5883x; 1.5883x over previous
//
#include <hip/hip_runtime.h>
#include <hip/hip_bf16.h>

typedef __hip_bfloat16 bf16;
typedef float f32x4 __attribute__((ext_vector_type(4)));
typedef short bf16x8 __attribute__((ext_vector_type(8)));

static __device__ __forceinline__ void gload_lds16(const void* g, void* l) {
    __builtin_amdgcn_global_load_lds(
        (const __attribute__((address_space(1))) void*)g,
        (__attribute__((address_space(3))) void*)l, 16, 0, 0);
}

static __device__ __forceinline__ short bf16bits(float v) {
    bf16 tb = __float2bfloat16(v);
    return *reinterpret_cast<short*>(&tb);
}

// ---------------- fp32 -> bf16 conversion (vectorized) ----------------
__global__ __launch_bounds__(256) void cvt_x_kernel(const float4* __restrict__ x,
                                                    bf16* __restrict__ xb, int n4) {
    int i = blockIdx.x * 256 + threadIdx.x;
    const int stride = gridDim.x * 256;
    for (; i < n4; i += stride) {
        float4 v = x[i];
        alignas(8) bf16 tmp[4];
        tmp[0] = __float2bfloat16(v.x);
        tmp[1] = __float2bfloat16(v.y);
        tmp[2] = __float2bfloat16(v.z);
        tmp[3] = __float2bfloat16(v.w);
        *reinterpret_cast<uint2*>(xb + 4l * i) = *reinterpret_cast<uint2*>(tmp);
    }
}

// ---------------- build W_eff^T (fold LoRA), bf16 ----------------
__global__ __launch_bounds__(256) void build_wefft_kernel(
    const float* __restrict__ qkv_w, const float* __restrict__ qa,
    const float* __restrict__ qb, const float* __restrict__ va,
    const float* __restrict__ vb, bf16* __restrict__ wt) {
    int idx = blockIdx.x * 256 + threadIdx.x;  // 1152*384 total
    int ncol = idx / 384;
    int k = idx - ncol * 384;
    float v = qkv_w[k * 1152 + ncol];
    if (ncol < 384) {
        float s = 0.f;
#pragma unroll
        for (int j = 0; j < 16; ++j) s += qa[k * 16 + j] * qb[j * 384 + ncol];
        v += s;
    } else if (ncol >= 768) {
        int nc = ncol - 768;
        float s = 0.f;
#pragma unroll
        for (int j = 0; j < 16; ++j) s += va[k * 16 + j] * vb[j * 384 + nc];
        v += s;
    }
    wt[(long)ncol * 384 + k] = __float2bfloat16(v);
}

// ---------------- transpose proj_w, bf16 ----------------
__global__ __launch_bounds__(256) void build_projt_kernel(const float* __restrict__ pw,
                                                          bf16* __restrict__ pt) {
    int idx = blockIdx.x * 256 + threadIdx.x;  // 384*384 total
    int ncol = idx / 384;
    int k = idx - ncol * 384;
    pt[(long)ncol * 384 + k] = __float2bfloat16(pw[k * 384 + ncol]);
}

// ---------------- combined rpb + mask bias: cbias[h][w][i*49+j] ----------------
__global__ __launch_bounds__(256) void build_cbias_kernel(const float* __restrict__ rpb_table,
                                                          const float* __restrict__ mask,
                                                          float* __restrict__ cbias) {
    int idx = blockIdx.x * 256 + threadIdx.x;  // 12*64*2401 = 1,843,968 = 7203*256
    int hw = idx / 2401;
    int ij = idx - hw * 2401;
    int h = hw >> 6, w = hw & 63;
    int i = ij / 49, j = ij - i * 49;
    int yi = i / 7, xi = i - yi * 7;
    int yj = j / 7, xj = j - yj * 7;
    int rel = (yi - yj + 6) * 13 + (xi - xj + 6);
    cbias[idx] = rpb_table[rel * 12 + h] + mask[w * 2401 + ij];
}

// ---------------- bf16 GEMM: C[M,N] = A[M,K] @ BT[N,K]^T + bias ----------------
template <bool OUT_BF16>
__global__ __launch_bounds__(256) void gemm_kernel(const bf16* __restrict__ A,
                                                   const bf16* __restrict__ BT,
                                                   const float* __restrict__ bias,
                                                   void* __restrict__ Cout, int N, int K) {
    __shared__ short Al[128 * 32];
    __shared__ short Bl[128 * 32];
    const int t = threadIdx.x;
    const int lane = t & 63;
    const int wave = t >> 6;
    const int wr = wave >> 1;
    const int wc = wave & 1;
    const long rowBase = (long)blockIdx.y * 128;
    const long colBase = (long)blockIdx.x * 128;

    f32x4 acc[4][4];
#pragma unroll
    for (int m = 0; m < 4; ++m)
#pragma unroll
        for (int n = 0; n < 4; ++n) acc[m][n] = (f32x4){0.f, 0.f, 0.f, 0.f};

    const int r0 = t >> 2;
    const int kc0 = (t & 3) * 8;

    for (int k0 = 0; k0 < K; k0 += 32) {
        __syncthreads();
        gload_lds16(A + (rowBase + r0) * K + k0 + kc0, &Al[t * 8]);
        gload_lds16(A + (rowBase + r0 + 64) * K + k0 + kc0, &Al[(t + 256) * 8]);
        gload_lds16(BT + (colBase + r0) * K + k0 + kc0, &Bl[t * 8]);
        gload_lds16(BT + (colBase + r0 + 64) * K + k0 + kc0, &Bl[(t + 256) * 8]);
        asm volatile("s_waitcnt vmcnt(0)" ::: "memory");
        __syncthreads();

        bf16x8 af[4], bfr[4];
        const int rsel = (lane >> 4) * 8;
#pragma unroll
        for (int m = 0; m < 4; ++m)
            af[m] = *(const bf16x8*)&Al[(wr * 64 + m * 16 + (lane & 15)) * 32 + rsel];
#pragma unroll
        for (int n = 0; n < 4; ++n)
            bfr[n] = *(const bf16x8*)&Bl[(wc * 64 + n * 16 + (lane & 15)) * 32 + rsel];
#pragma unroll
        for (int m = 0; m < 4; ++m)
#pragma unroll
            for (int n = 0; n < 4; ++n)
                acc[m][n] = __builtin_amdgcn_mfma_f32_16x16x32_bf16(af[m], bfr[n],
                                                                    acc[m][n], 0, 0, 0);
    }

    const int crow0 = wr * 64 + ((t & 63) >> 4) * 4;
    const long ccol0 = colBase + wc * 64 + (lane & 15);
#pragma unroll
    for (int m = 0; m < 4; ++m) {
#pragma unroll
        for (int n = 0; n < 4; ++n) {
            const long col = ccol0 + n * 16;
            const float bv = bias[col];
#pragma unroll
            for (int r = 0; r < 4; ++r) {
                const long row = rowBase + crow0 + m * 16 + r;
                float v = acc[m][n][r] + bv;
                if (OUT_BF16)
                    ((bf16*)Cout)[row * N + col] = __float2bfloat16(v);
                else
                    ((float*)Cout)[row * N + col] = v;
            }
        }
    }
}

// ---------------- MFMA window attention: one WAVE per (b, h) ----------------
// Per-wave LDS (shorts): Q [64][40] @0, K [64][40] @2560, VT[32][64] @5120 (swz),
// P [64][64] @0 (swz, overlays Q/K after QK^T). Total 7168 shorts = 14336 B/wave.
__global__ __launch_bounds__(256) void attn_kernel(const bf16* __restrict__ qkv,
                                                   const float* __restrict__ cbias,
                                                   bf16* __restrict__ out) {
    __shared__ short lds[4 * 7168];
    const int t = threadIdx.x, lane = t & 63, wave = t >> 6;
    short* W = lds + wave * 7168;
    const int bh = blockIdx.x * 4 + wave;
    const int b = bh / 12, h = bh - b * 12;
    const int g = lane >> 4, c = lane & 15;
    const int w = b & 63;

    // ---- stage: zero VT, load Q,K row-major (stride 40), V transposed+swizzled
#pragma unroll
    for (int z = 0; z < 4; ++z)
        *(uint4*)&W[5120 + (z * 64 + lane) * 8] = (uint4){0u, 0u, 0u, 0u};

    const size_t base = (size_t)b * 49 * 1152 + h * 32;
    for (int c4 = lane; c4 < 196; c4 += 64) {
        int n = c4 >> 2, o = (c4 & 3) * 8;
        size_t gaddr = base + (size_t)n * 1152 + o;
        uint4 qv = *(const uint4*)&qkv[gaddr];
        uint4 kv = *(const uint4*)&qkv[gaddr + 384];
        uint4 vv = *(const uint4*)&qkv[gaddr + 768];
        *(uint4*)&W[n * 40 + o] = qv;
        *(uint4*)&W[2560 + n * 40 + o] = kv;
        alignas(16) short tmp[8];
        *(uint4*)tmp = vv;
#pragma unroll
        for (int j = 0; j < 8; ++j) {
            int d = o + j;
            W[5120 + ((d * 64 + n) ^ ((d & 7) << 3))] = tmp[j];
        }
    }
    __syncthreads();

    // ---- QK^T: S[i][j], i=16mt+g*4+r, j=16nt+c
    bf16x8 aq[4], bk[4];
#pragma unroll
    for (int mt = 0; mt < 4; ++mt) aq[mt] = *(const bf16x8*)&W[(mt * 16 + c) * 40 + g * 8];
#pragma unroll
    for (int nt = 0; nt < 4; ++nt) bk[nt] = *(const bf16x8*)&W[2560 + (nt * 16 + c) * 40 + g * 8];
    f32x4 S[4][4];
#pragma unroll
    for (int mt = 0; mt < 4; ++mt)
#pragma unroll
        for (int nt = 0; nt < 4; ++nt)
            S[mt][nt] = __builtin_amdgcn_mfma_f32_16x16x32_bf16(aq[mt], bk[nt],
                                                                (f32x4){0.f, 0.f, 0.f, 0.f}, 0, 0, 0);

    // ---- bias + softmax (rows lane-group-local; reduce over nt + 16-lane shfl)
    const float scale = 0.17677669529663687f;
    const float* cb = cbias + (size_t)((h << 6) | w) * 2401;
    float inv[16];
#pragma unroll
    for (int mt = 0; mt < 4; ++mt) {
#pragma unroll
        for (int nt = 0; nt < 4; ++nt) {
            int j = nt * 16 + c;
#pragma unroll
            for (int r = 0; r < 4; ++r) {
                int i = mt * 16 + g * 4 + r;
                float v = S[mt][nt][r] * scale;
                if (j < 49 && i < 49) v += cb[i * 49 + j];
                S[mt][nt][r] = (j < 49) ? v : -INFINITY;
            }
        }
#pragma unroll
        for (int r = 0; r < 4; ++r) {
            float m = fmaxf(fmaxf(S[mt][0][r], S[mt][1][r]), fmaxf(S[mt][2][r], S[mt][3][r]));
            m = fmaxf(m, __shfl_xor(m, 1));
            m = fmaxf(m, __shfl_xor(m, 2));
            m = fmaxf(m, __shfl_xor(m, 4));
            m = fmaxf(m, __shfl_xor(m, 8));
            float s = 0.f;
#pragma unroll
            for (int nt = 0; nt < 4; ++nt) {
                float e = __expf(S[mt][nt][r] - m);
                S[mt][nt][r] = e;
                s += e;
            }
            s += __shfl_xor(s, 1);
            s += __shfl_xor(s, 2);
            s += __shfl_xor(s, 4);
            s += __shfl_xor(s, 8);
            inv[mt * 4 + r] = 1.f / s;
        }
    }

    // ---- P -> bf16 -> LDS (swizzled), overlays Q/K
    __syncthreads();
#pragma unroll
    for (int mt = 0; mt < 4; ++mt)
#pragma unroll
        for (int nt = 0; nt < 4; ++nt)
#pragma unroll
            for (int r = 0; r < 4; ++r) {
                int i = mt * 16 + g * 4 + r, j = nt * 16 + c;
                W[(i * 64 + j) ^ ((i & 7) << 3)] = bf16bits(S[mt][nt][r]);
            }
    __syncthreads();

    // ---- PV: O[i][d] = sum_j P[i][j] * VT[d][j]
    f32x4 O[4][2];
#pragma unroll
    for (int mt = 0; mt < 4; ++mt)
#pragma unroll
        for (int dt = 0; dt < 2; ++dt) O[mt][dt] = (f32x4){0.f, 0.f, 0.f, 0.f};
#pragma unroll
    for (int ks = 0; ks < 2; ++ks) {
        bf16x8 pa[4], vb2[2];
#pragma unroll
        for (int mt = 0; mt < 4; ++mt) {
            int i = mt * 16 + c;
            pa[mt] = *(const bf16x8*)&W[(i * 64 + ks * 32 + g * 8) ^ ((i & 7) << 3)];
        }
#pragma unroll
        for (int dt = 0; dt < 2; ++dt) {
            int d = dt * 16 + c;
            vb2[dt] = *(const bf16x8*)&W[5120 + ((d * 64 + ks * 32 + g * 8) ^ ((d & 7) << 3))];
        }
#pragma unroll
        for (int mt = 0; mt < 4; ++mt)
#pragma unroll
            for (int dt = 0; dt < 2; ++dt)
                O[mt][dt] = __builtin_amdgcn_mfma_f32_16x16x32_bf16(pa[mt], vb2[dt],
                                                                    O[mt][dt], 0, 0, 0);
    }

    // ---- epilogue: normalize by 1/rowsum, store bf16
#pragma unroll
    for (int mt = 0; mt < 4; ++mt)
#pragma unroll
        for (int r = 0; r < 4; ++r) {
            int i = mt * 16 + g * 4 + r;
            if (i < 49) {
#pragma unroll
                for (int dt = 0; dt < 2; ++dt) {
                    int d = dt * 16 + c;
                    out[((size_t)(b * 49 + i)) * 384 + h * 32 + d] =
                        __float2bfloat16(O[mt][dt][r] * inv[mt * 4 + r]);
                }
            }
        }
}

extern "C" void kernel_launch(void* const* d_in, const int* in_sizes, int n_in,
                              void* d_out, int out_size, void* d_ws, size_t ws_size,
                              hipStream_t stream) {
    (void)in_sizes; (void)n_in; (void)out_size; (void)ws_size;
    const float* x      = (const float*)d_in[0];
    const float* mask   = (const float*)d_in[1];
    const float* qkv_w  = (const float*)d_in[2];
    const float* qkv_b  = (const float*)d_in[3];
    const float* qa_w   = (const float*)d_in[4];
    const float* qb_w   = (const float*)d_in[5];
    const float* va_w   = (const float*)d_in[6];
    const float* vb_w   = (const float*)d_in[7];
    const float* rpb    = (const float*)d_in[8];
    const float* proj_w = (const float*)d_in[9];
    const float* proj_b = (const float*)d_in[10];

    char* ws = (char*)d_ws;
    bf16* xb    = (bf16*)(ws);                    // 77,070,336 B (dead after gemm1)
    bf16* wefft = (bf16*)(ws + 77070336);
    bf16* projt = (bf16*)(ws + 77955072);
    bf16* qkv   = (bf16*)(ws + 78249984);         // 231,211,008 B
    bf16* attno = (bf16*)(ws + 309460992);        // 77,070,336 B
    float* cbias = (float*)(ws);                  // 7.4 MB, reuses xb region AFTER gemm1

    cvt_x_kernel<<<2048, 256, 0, stream>>>((const float4*)x, xb, 9633792);
    build_wefft_kernel<<<1728, 256, 0, stream>>>(qkv_w, qa_w, qb_w, va_w, vb_w, wefft);
    build_projt_kernel<<<576, 256, 0, stream>>>(proj_w, projt);
    gemm_kernel<true><<<dim3(9, 784), 256, 0, stream>>>(xb, wefft, qkv_b, qkv, 1152, 384);
    // xb dead now; cbias may overwrite it (stream-ordered)
    build_cbias_kernel<<<7203, 256, 0, stream>>>(rpb, mask, cbias);
    attn_kernel<<<6144, 256, 0, stream>>>(qkv, cbias, attno);
    gemm_kernel<false><<<dim3(3, 784), 256, 0, stream>>>(attno, projt, proj_b, d_out, 384, 384);
}

// Round 4
// 407.700 us; speedup vs baseline: 1.6847x; 1.0607x over previous
//
#include <hip/hip_runtime.h>
#include <hip/hip_bf16.h>

typedef __hip_bfloat16 bf16;
typedef float f32x4 __attribute__((ext_vector_type(4)));
typedef short bf16x8 __attribute__((ext_vector_type(8)));

static __device__ __forceinline__ void gload_lds16(const void* g, void* l) {
    __builtin_amdgcn_global_load_lds(
        (const __attribute__((address_space(1))) void*)g,
        (__attribute__((address_space(3))) void*)l, 16, 0, 0);
}

static __device__ __forceinline__ short bf16bits(float v) {
    bf16 tb = __float2bfloat16(v);
    return *reinterpret_cast<short*>(&tb);
}

// ---------------- build W_eff^T (fold LoRA), bf16 ----------------
__global__ __launch_bounds__(256) void build_wefft_kernel(
    const float* __restrict__ qkv_w, const float* __restrict__ qa,
    const float* __restrict__ qb, const float* __restrict__ va,
    const float* __restrict__ vb, bf16* __restrict__ wt) {
    int idx = blockIdx.x * 256 + threadIdx.x;  // 1152*384 total
    int ncol = idx / 384;
    int k = idx - ncol * 384;
    float v = qkv_w[k * 1152 + ncol];
    if (ncol < 384) {
        float s = 0.f;
#pragma unroll
        for (int j = 0; j < 16; ++j) s += qa[k * 16 + j] * qb[j * 384 + ncol];
        v += s;
    } else if (ncol >= 768) {
        int nc = ncol - 768;
        float s = 0.f;
#pragma unroll
        for (int j = 0; j < 16; ++j) s += va[k * 16 + j] * vb[j * 384 + nc];
        v += s;
    }
    wt[(long)ncol * 384 + k] = __float2bfloat16(v);
}

// ---------------- transpose proj_w, bf16 ----------------
__global__ __launch_bounds__(256) void build_projt_kernel(const float* __restrict__ pw,
                                                          bf16* __restrict__ pt) {
    int idx = blockIdx.x * 256 + threadIdx.x;  // 384*384 total
    int ncol = idx / 384;
    int k = idx - ncol * 384;
    pt[(long)ncol * 384 + k] = __float2bfloat16(pw[k * 384 + ncol]);
}

// ---------------- combined rpb + mask bias: cbias[h][w][i*49+j] ----------------
__global__ __launch_bounds__(256) void build_cbias_kernel(const float* __restrict__ rpb_table,
                                                          const float* __restrict__ mask,
                                                          float* __restrict__ cbias) {
    int idx = blockIdx.x * 256 + threadIdx.x;  // 12*64*2401 = 7203*256
    int hw = idx / 2401;
    int ij = idx - hw * 2401;
    int h = hw >> 6, w = hw & 63;
    int i = ij / 49, j = ij - i * 49;
    int yi = i / 7, xi = i - yi * 7;
    int yj = j / 7, xj = j - yj * 7;
    int rel = (yi - yj + 6) * 13 + (xi - xj + 6);
    cbias[idx] = rpb_table[rel * 12 + h] + mask[w * 2401 + ij];
}

// ---------------- GEMM: C[M,N] = A[M,K] @ BT[N,K]^T + bias ----------------
// 128x128 tile, BK=64. LDS linear dest; XOR-swizzled (16B-block ^ row&7) global
// source; same XOR on fragment ds_read_b128 -> 2-way (free) bank access.
// A_FP32: A reg-staged with fp32->bf16 cvt (fuses the cvt pass); else gload_lds.
// 1-D grid with bijective XCD swizzle (nwg % 8 == 0).
template <bool A_FP32, bool OUT_BF16>
__global__ __launch_bounds__(256) void gemm_kernel(const void* __restrict__ Av,
                                                   const bf16* __restrict__ BT,
                                                   const float* __restrict__ bias,
                                                   void* __restrict__ Cout,
                                                   int N, int K, int nxb, int nwg) {
    __shared__ short Al[128 * 64];
    __shared__ short Bl[128 * 64];
    const int t = threadIdx.x;
    const int lane = t & 63;
    const int wave = t >> 6;
    const int wr = wave >> 1;
    const int wc = wave & 1;
    const int g = lane >> 4, c = lane & 15;

    // XCD swizzle: consecutive by-groups per XCD (nwg divisible by 8)
    const int q8 = nwg >> 3;
    const int wgid = (blockIdx.x & 7) * q8 + (blockIdx.x >> 3);
    const int by = wgid / nxb;
    const int bx = wgid - by * nxb;
    const long rowBase = (long)by * 128;
    const long colBase = (long)bx * 128;

    f32x4 acc[4][4];
#pragma unroll
    for (int m = 0; m < 4; ++m)
#pragma unroll
        for (int n = 0; n < 4; ++n) acc[m][n] = (f32x4){0.f, 0.f, 0.f, 0.f};

    for (int k0 = 0; k0 < K; k0 += 64) {
        __syncthreads();  // readers done with previous tile
        // ---- stage B: gload_lds, XORed per-lane source, linear dest
#pragma unroll
        for (int it = 0; it < 4; ++it) {
            int chunk = it * 256 + t;
            int row = chunk >> 3;
            int blk = lane & 7;  // == chunk & 7
            gload_lds16(BT + (size_t)(colBase + row) * K + k0 + ((blk ^ (row & 7)) * 8),
                        &Bl[(it * 256 + wave * 64) * 8]);
        }
        // ---- stage A
        if (A_FP32) {
            const float* Af = (const float*)Av;
#pragma unroll
            for (int it = 0; it < 4; ++it) {
                int chunk = it * 256 + t;
                int row = chunk >> 3;
                int blk = chunk & 7;
                const float* src = Af + (size_t)(rowBase + row) * K + k0 + ((blk ^ (row & 7)) * 8);
                float4 v0 = *(const float4*)src;
                float4 v1 = *(const float4*)(src + 4);
                alignas(16) short tmp[8];
                tmp[0] = bf16bits(v0.x); tmp[1] = bf16bits(v0.y);
                tmp[2] = bf16bits(v0.z); tmp[3] = bf16bits(v0.w);
                tmp[4] = bf16bits(v1.x); tmp[5] = bf16bits(v1.y);
                tmp[6] = bf16bits(v1.z); tmp[7] = bf16bits(v1.w);
                *(uint4*)&Al[chunk * 8] = *(const uint4*)tmp;
            }
        } else {
            const bf16* Ab = (const bf16*)Av;
#pragma unroll
            for (int it = 0; it < 4; ++it) {
                int chunk = it * 256 + t;
                int row = chunk >> 3;
                int blk = lane & 7;
                gload_lds16(Ab + (size_t)(rowBase + row) * K + k0 + ((blk ^ (row & 7)) * 8),
                            &Al[(it * 256 + wave * 64) * 8]);
            }
        }
        asm volatile("s_waitcnt vmcnt(0)" ::: "memory");
        __syncthreads();

        // ---- compute: 2 k-slices x 16 MFMA
#pragma unroll
        for (int ks = 0; ks < 2; ++ks) {
            bf16x8 af[4], bfr[4];
#pragma unroll
            for (int m = 0; m < 4; ++m) {
                int row = wr * 64 + m * 16 + c;
                af[m] = *(const bf16x8*)&Al[row * 64 + (((ks * 4 + g) ^ (c & 7)) * 8)];
            }
#pragma unroll
            for (int n = 0; n < 4; ++n) {
                int row = wc * 64 + n * 16 + c;
                bfr[n] = *(const bf16x8*)&Bl[row * 64 + (((ks * 4 + g) ^ (c & 7)) * 8)];
            }
#pragma unroll
            for (int m = 0; m < 4; ++m)
#pragma unroll
                for (int n = 0; n < 4; ++n)
                    acc[m][n] = __builtin_amdgcn_mfma_f32_16x16x32_bf16(af[m], bfr[n],
                                                                        acc[m][n], 0, 0, 0);
        }
    }

    // epilogue: C/D layout col=lane&15, row=(lane>>4)*4+reg
    const int crow0 = wr * 64 + g * 4;
    const long ccol0 = colBase + wc * 64 + c;
#pragma unroll
    for (int m = 0; m < 4; ++m) {
#pragma unroll
        for (int n = 0; n < 4; ++n) {
            const long col = ccol0 + n * 16;
            const float bv = bias[col];
#pragma unroll
            for (int r = 0; r < 4; ++r) {
                const long row = rowBase + crow0 + m * 16 + r;
                float v = acc[m][n][r] + bv;
                if (OUT_BF16)
                    ((bf16*)Cout)[row * N + col] = __float2bfloat16(v);
                else
                    ((float*)Cout)[row * N + col] = v;
            }
        }
    }
}

// ---------------- MFMA window attention: one WAVE per (b, h) ----------------
__global__ __launch_bounds__(256) void attn_kernel(const bf16* __restrict__ qkv,
                                                   const float* __restrict__ cbias,
                                                   bf16* __restrict__ out) {
    __shared__ short lds[4 * 7168];
    const int t = threadIdx.x, lane = t & 63, wave = t >> 6;
    short* W = lds + wave * 7168;
    const int bh = blockIdx.x * 4 + wave;
    const int b = bh / 12, h = bh - b * 12;
    const int g = lane >> 4, c = lane & 15;
    const int w = b & 63;

#pragma unroll
    for (int z = 0; z < 4; ++z)
        *(uint4*)&W[5120 + (z * 64 + lane) * 8] = (uint4){0u, 0u, 0u, 0u};

    const size_t base = (size_t)b * 49 * 1152 + h * 32;
    for (int c4 = lane; c4 < 196; c4 += 64) {
        int n = c4 >> 2, o = (c4 & 3) * 8;
        size_t gaddr = base + (size_t)n * 1152 + o;
        uint4 qv = *(const uint4*)&qkv[gaddr];
        uint4 kv = *(const uint4*)&qkv[gaddr + 384];
        uint4 vv = *(const uint4*)&qkv[gaddr + 768];
        *(uint4*)&W[n * 40 + o] = qv;
        *(uint4*)&W[2560 + n * 40 + o] = kv;
        alignas(16) short tmp[8];
        *(uint4*)tmp = vv;
#pragma unroll
        for (int j = 0; j < 8; ++j) {
            int d = o + j;
            W[5120 + ((d * 64 + n) ^ ((d & 7) << 3))] = tmp[j];
        }
    }
    __syncthreads();

    bf16x8 aq[4], bk[4];
#pragma unroll
    for (int mt = 0; mt < 4; ++mt) aq[mt] = *(const bf16x8*)&W[(mt * 16 + c) * 40 + g * 8];
#pragma unroll
    for (int nt = 0; nt < 4; ++nt) bk[nt] = *(const bf16x8*)&W[2560 + (nt * 16 + c) * 40 + g * 8];
    f32x4 S[4][4];
#pragma unroll
    for (int mt = 0; mt < 4; ++mt)
#pragma unroll
        for (int nt = 0; nt < 4; ++nt)
            S[mt][nt] = __builtin_amdgcn_mfma_f32_16x16x32_bf16(aq[mt], bk[nt],
                                                                (f32x4){0.f, 0.f, 0.f, 0.f}, 0, 0, 0);

    const float scale = 0.17677669529663687f;
    const float* cb = cbias + (size_t)((h << 6) | w) * 2401;
    float inv[16];
#pragma unroll
    for (int mt = 0; mt < 4; ++mt) {
#pragma unroll
        for (int nt = 0; nt < 4; ++nt) {
            int j = nt * 16 + c;
#pragma unroll
            for (int r = 0; r < 4; ++r) {
                int i = mt * 16 + g * 4 + r;
                float v = S[mt][nt][r] * scale;
                if (j < 49 && i < 49) v += cb[i * 49 + j];
                S[mt][nt][r] = (j < 49) ? v : -INFINITY;
            }
        }
#pragma unroll
        for (int r = 0; r < 4; ++r) {
            float m = fmaxf(fmaxf(S[mt][0][r], S[mt][1][r]), fmaxf(S[mt][2][r], S[mt][3][r]));
            m = fmaxf(m, __shfl_xor(m, 1));
            m = fmaxf(m, __shfl_xor(m, 2));
            m = fmaxf(m, __shfl_xor(m, 4));
            m = fmaxf(m, __shfl_xor(m, 8));
            float s = 0.f;
#pragma unroll
            for (int nt = 0; nt < 4; ++nt) {
                float e = __expf(S[mt][nt][r] - m);
                S[mt][nt][r] = e;
                s += e;
            }
            s += __shfl_xor(s, 1);
            s += __shfl_xor(s, 2);
            s += __shfl_xor(s, 4);
            s += __shfl_xor(s, 8);
            inv[mt * 4 + r] = 1.f / s;
        }
    }

    __syncthreads();
#pragma unroll
    for (int mt = 0; mt < 4; ++mt)
#pragma unroll
        for (int nt = 0; nt < 4; ++nt)
#pragma unroll
            for (int r = 0; r < 4; ++r) {
                int i = mt * 16 + g * 4 + r, j = nt * 16 + c;
                W[(i * 64 + j) ^ ((i & 7) << 3)] = bf16bits(S[mt][nt][r]);
            }
    __syncthreads();

    f32x4 O[4][2];
#pragma unroll
    for (int mt = 0; mt < 4; ++mt)
#pragma unroll
        for (int dt = 0; dt < 2; ++dt) O[mt][dt] = (f32x4){0.f, 0.f, 0.f, 0.f};
#pragma unroll
    for (int ks = 0; ks < 2; ++ks) {
        bf16x8 pa[4], vb2[2];
#pragma unroll
        for (int mt = 0; mt < 4; ++mt) {
            int i = mt * 16 + c;
            pa[mt] = *(const bf16x8*)&W[(i * 64 + ks * 32 + g * 8) ^ ((i & 7) << 3)];
        }
#pragma unroll
        for (int dt = 0; dt < 2; ++dt) {
            int d = dt * 16 + c;
            vb2[dt] = *(const bf16x8*)&W[5120 + ((d * 64 + ks * 32 + g * 8) ^ ((d & 7) << 3))];
        }
#pragma unroll
        for (int mt = 0; mt < 4; ++mt)
#pragma unroll
            for (int dt = 0; dt < 2; ++dt)
                O[mt][dt] = __builtin_amdgcn_mfma_f32_16x16x32_bf16(pa[mt], vb2[dt],
                                                                    O[mt][dt], 0, 0, 0);
    }

#pragma unroll
    for (int mt = 0; mt < 4; ++mt)
#pragma unroll
        for (int r = 0; r < 4; ++r) {
            int i = mt * 16 + g * 4 + r;
            if (i < 49) {
#pragma unroll
                for (int dt = 0; dt < 2; ++dt) {
                    int d = dt * 16 + c;
                    out[((size_t)(b * 49 + i)) * 384 + h * 32 + d] =
                        __float2bfloat16(O[mt][dt][r] * inv[mt * 4 + r]);
                }
            }
        }
}

extern "C" void kernel_launch(void* const* d_in, const int* in_sizes, int n_in,
                              void* d_out, int out_size, void* d_ws, size_t ws_size,
                              hipStream_t stream) {
    (void)in_sizes; (void)n_in; (void)out_size; (void)ws_size;
    const float* x      = (const float*)d_in[0];
    const float* mask   = (const float*)d_in[1];
    const float* qkv_w  = (const float*)d_in[2];
    const float* qkv_b  = (const float*)d_in[3];
    const float* qa_w   = (const float*)d_in[4];
    const float* qb_w   = (const float*)d_in[5];
    const float* va_w   = (const float*)d_in[6];
    const float* vb_w   = (const float*)d_in[7];
    const float* rpb    = (const float*)d_in[8];
    const float* proj_w = (const float*)d_in[9];
    const float* proj_b = (const float*)d_in[10];

    char* ws = (char*)d_ws;
    bf16* wefft  = (bf16*)(ws);                    //    884,736 B
    bf16* projt  = (bf16*)(ws + 884736);           //    294,912 B
    float* cbias = (float*)(ws + 1179648);         //  7,375,872 B
    bf16* qkv    = (bf16*)(ws + 8555520);          // 231,211,008 B
    bf16* attno  = (bf16*)(ws + 239766528);        // 77,070,336 B (total ~317 MB)

    build_wefft_kernel<<<1728, 256, 0, stream>>>(qkv_w, qa_w, qb_w, va_w, vb_w, wefft);
    build_projt_kernel<<<576, 256, 0, stream>>>(proj_w, projt);
    build_cbias_kernel<<<7203, 256, 0, stream>>>(rpb, mask, cbias);
    // qkv[100352,1152] = cvt_bf16(x)[100352,384] @ wefft^T + qkv_b  (cvt fused)
    gemm_kernel<true, true><<<7056, 256, 0, stream>>>(x, wefft, qkv_b, qkv, 1152, 384, 9, 7056);
    attn_kernel<<<6144, 256, 0, stream>>>(qkv, cbias, attno);
    // out[100352,384] = attno @ projt^T + proj_b  (fp32)
    gemm_kernel<false, false><<<2352, 256, 0, stream>>>(attno, projt, proj_b, d_out, 384, 384, 3, 2352);
}

// Round 5
// 401.086 us; speedup vs baseline: 1.7125x; 1.0165x over previous
//
#include <hip/hip_runtime.h>
#include <hip/hip_bf16.h>

typedef __hip_bfloat16 bf16;
typedef float f32x4 __attribute__((ext_vector_type(4)));
typedef short bf16x8 __attribute__((ext_vector_type(8)));

static __device__ __forceinline__ void gload_lds16(const void* g, void* l) {
    __builtin_amdgcn_global_load_lds(
        (const __attribute__((address_space(1))) void*)g,
        (__attribute__((address_space(3))) void*)l, 16, 0, 0);
}

static __device__ __forceinline__ short bf16bits(float v) {
    bf16 tb = __float2bfloat16(v);
    return *reinterpret_cast<short*>(&tb);
}

// ---------------- fp32 -> bf16 conversion (vectorized) ----------------
__global__ __launch_bounds__(256) void cvt_x_kernel(const float4* __restrict__ x,
                                                    bf16* __restrict__ xb, int n4) {
    int i = blockIdx.x * 256 + threadIdx.x;
    const int stride = gridDim.x * 256;
    for (; i < n4; i += stride) {
        float4 v = x[i];
        alignas(8) bf16 tmp[4];
        tmp[0] = __float2bfloat16(v.x);
        tmp[1] = __float2bfloat16(v.y);
        tmp[2] = __float2bfloat16(v.z);
        tmp[3] = __float2bfloat16(v.w);
        *reinterpret_cast<uint2*>(xb + 4l * i) = *reinterpret_cast<uint2*>(tmp);
    }
}

// ---------------- build W_eff^T (fold LoRA), bf16 ----------------
__global__ __launch_bounds__(256) void build_wefft_kernel(
    const float* __restrict__ qkv_w, const float* __restrict__ qa,
    const float* __restrict__ qb, const float* __restrict__ va,
    const float* __restrict__ vb, bf16* __restrict__ wt) {
    int idx = blockIdx.x * 256 + threadIdx.x;  // 1152*384 total
    int ncol = idx / 384;
    int k = idx - ncol * 384;
    float v = qkv_w[k * 1152 + ncol];
    if (ncol < 384) {
        float s = 0.f;
#pragma unroll
        for (int j = 0; j < 16; ++j) s += qa[k * 16 + j] * qb[j * 384 + ncol];
        v += s;
    } else if (ncol >= 768) {
        int nc = ncol - 768;
        float s = 0.f;
#pragma unroll
        for (int j = 0; j < 16; ++j) s += va[k * 16 + j] * vb[j * 384 + nc];
        v += s;
    }
    wt[(long)ncol * 384 + k] = __float2bfloat16(v);
}

// ---------------- transpose proj_w, bf16 ----------------
__global__ __launch_bounds__(256) void build_projt_kernel(const float* __restrict__ pw,
                                                          bf16* __restrict__ pt) {
    int idx = blockIdx.x * 256 + threadIdx.x;  // 384*384 total
    int ncol = idx / 384;
    int k = idx - ncol * 384;
    pt[(long)ncol * 384 + k] = __float2bfloat16(pw[k * 384 + ncol]);
}

// ---------------- combined rpb + mask bias: cbias[h][w][i*49+j] ----------------
__global__ __launch_bounds__(256) void build_cbias_kernel(const float* __restrict__ rpb_table,
                                                          const float* __restrict__ mask,
                                                          float* __restrict__ cbias) {
    int idx = blockIdx.x * 256 + threadIdx.x;  // 12*64*2401 = 7203*256
    int hw = idx / 2401;
    int ij = idx - hw * 2401;
    int h = hw >> 6, w = hw & 63;
    int i = ij / 49, j = ij - i * 49;
    int yi = i / 7, xi = i - yi * 7;
    int yj = j / 7, xj = j - yj * 7;
    int rel = (yi - yj + 6) * 13 + (xi - xj + 6);
    cbias[idx] = rpb_table[rel * 12 + h] + mask[w * 2401 + ij];
}

// ---------------- GEMM: C[M,N] = A[M,K] @ BT[N,K]^T + bias ----------------
// 128x128 tile, BK=64. Both operands staged via global_load_lds (linear dest)
// with XOR-swizzled per-lane global SOURCE (16B-chunk ^ row&7); fragment
// ds_read_b128 applies the same XOR -> 2-way (free) bank access, 0 conflicts.
// 1-D grid with bijective XCD swizzle (nwg % 8 == 0).
template <bool OUT_BF16>
__global__ __launch_bounds__(256) void gemm_kernel(const bf16* __restrict__ A,
                                                   const bf16* __restrict__ BT,
                                                   const float* __restrict__ bias,
                                                   void* __restrict__ Cout,
                                                   int N, int K, int nxb, int nwg) {
    __shared__ short Al[128 * 64];
    __shared__ short Bl[128 * 64];
    const int t = threadIdx.x;
    const int lane = t & 63;
    const int wave = t >> 6;
    const int wr = wave >> 1;
    const int wc = wave & 1;
    const int g = lane >> 4, c = lane & 15;

    // XCD swizzle: consecutive wg-groups per XCD (nwg divisible by 8)
    const int q8 = nwg >> 3;
    const int wgid = (blockIdx.x & 7) * q8 + (blockIdx.x >> 3);
    const int by = wgid / nxb;
    const int bx = wgid - by * nxb;
    const long rowBase = (long)by * 128;
    const long colBase = (long)bx * 128;

    f32x4 acc[4][4];
#pragma unroll
    for (int m = 0; m < 4; ++m)
#pragma unroll
        for (int n = 0; n < 4; ++n) acc[m][n] = (f32x4){0.f, 0.f, 0.f, 0.f};

    for (int k0 = 0; k0 < K; k0 += 64) {
        __syncthreads();  // readers done with previous tile
#pragma unroll
        for (int it = 0; it < 4; ++it) {
            int chunk = it * 256 + t;
            int row = chunk >> 3;
            int blk = lane & 7;  // == chunk & 7
            gload_lds16(A + (size_t)(rowBase + row) * K + k0 + ((blk ^ (row & 7)) * 8),
                        &Al[(it * 256 + wave * 64) * 8]);
            gload_lds16(BT + (size_t)(colBase + row) * K + k0 + ((blk ^ (row & 7)) * 8),
                        &Bl[(it * 256 + wave * 64) * 8]);
        }
        asm volatile("s_waitcnt vmcnt(0)" ::: "memory");
        __syncthreads();

        // ---- compute: 2 k-slices x 16 MFMA
#pragma unroll
        for (int ks = 0; ks < 2; ++ks) {
            bf16x8 af[4], bfr[4];
#pragma unroll
            for (int m = 0; m < 4; ++m) {
                int row = wr * 64 + m * 16 + c;
                af[m] = *(const bf16x8*)&Al[row * 64 + (((ks * 4 + g) ^ (c & 7)) * 8)];
            }
#pragma unroll
            for (int n = 0; n < 4; ++n) {
                int row = wc * 64 + n * 16 + c;
                bfr[n] = *(const bf16x8*)&Bl[row * 64 + (((ks * 4 + g) ^ (c & 7)) * 8)];
            }
#pragma unroll
            for (int m = 0; m < 4; ++m)
#pragma unroll
                for (int n = 0; n < 4; ++n)
                    acc[m][n] = __builtin_amdgcn_mfma_f32_16x16x32_bf16(af[m], bfr[n],
                                                                        acc[m][n], 0, 0, 0);
        }
    }

    // epilogue: C/D layout col=lane&15, row=(lane>>4)*4+reg
    const int crow0 = wr * 64 + g * 4;
    const long ccol0 = colBase + wc * 64 + c;
#pragma unroll
    for (int m = 0; m < 4; ++m) {
#pragma unroll
        for (int n = 0; n < 4; ++n) {
            const long col = ccol0 + n * 16;
            const float bv = bias[col];
#pragma unroll
            for (int r = 0; r < 4; ++r) {
                const long row = rowBase + crow0 + m * 16 + r;
                float v = acc[m][n][r] + bv;
                if (OUT_BF16)
                    ((bf16*)Cout)[row * N + col] = __float2bfloat16(v);
                else
                    ((float*)Cout)[row * N + col] = v;
            }
        }
    }
}

// ---------------- MFMA window attention: one WAVE per (b, h) ----------------
__global__ __launch_bounds__(256) void attn_kernel(const bf16* __restrict__ qkv,
                                                   const float* __restrict__ cbias,
                                                   bf16* __restrict__ out) {
    __shared__ short lds[4 * 7168];
    const int t = threadIdx.x, lane = t & 63, wave = t >> 6;
    short* W = lds + wave * 7168;
    const int bh = blockIdx.x * 4 + wave;
    const int b = bh / 12, h = bh - b * 12;
    const int g = lane >> 4, c = lane & 15;
    const int w = b & 63;

#pragma unroll
    for (int z = 0; z < 4; ++z)
        *(uint4*)&W[5120 + (z * 64 + lane) * 8] = (uint4){0u, 0u, 0u, 0u};

    const size_t base = (size_t)b * 49 * 1152 + h * 32;
    for (int c4 = lane; c4 < 196; c4 += 64) {
        int n = c4 >> 2, o = (c4 & 3) * 8;
        size_t gaddr = base + (size_t)n * 1152 + o;
        uint4 qv = *(const uint4*)&qkv[gaddr];
        uint4 kv = *(const uint4*)&qkv[gaddr + 384];
        uint4 vv = *(const uint4*)&qkv[gaddr + 768];
        *(uint4*)&W[n * 40 + o] = qv;
        *(uint4*)&W[2560 + n * 40 + o] = kv;
        alignas(16) short tmp[8];
        *(uint4*)tmp = vv;
#pragma unroll
        for (int j = 0; j < 8; ++j) {
            int d = o + j;
            W[5120 + ((d * 64 + n) ^ ((d & 7) << 3))] = tmp[j];
        }
    }
    __syncthreads();

    bf16x8 aq[4], bk[4];
#pragma unroll
    for (int mt = 0; mt < 4; ++mt) aq[mt] = *(const bf16x8*)&W[(mt * 16 + c) * 40 + g * 8];
#pragma unroll
    for (int nt = 0; nt < 4; ++nt) bk[nt] = *(const bf16x8*)&W[2560 + (nt * 16 + c) * 40 + g * 8];
    f32x4 S[4][4];
#pragma unroll
    for (int mt = 0; mt < 4; ++mt)
#pragma unroll
        for (int nt = 0; nt < 4; ++nt)
            S[mt][nt] = __builtin_amdgcn_mfma_f32_16x16x32_bf16(aq[mt], bk[nt],
                                                                (f32x4){0.f, 0.f, 0.f, 0.f}, 0, 0, 0);

    const float scale = 0.17677669529663687f;
    const float* cb = cbias + (size_t)((h << 6) | w) * 2401;
    float inv[16];
#pragma unroll
    for (int mt = 0; mt < 4; ++mt) {
#pragma unroll
        for (int nt = 0; nt < 4; ++nt) {
            int j = nt * 16 + c;
#pragma unroll
            for (int r = 0; r < 4; ++r) {
                int i = mt * 16 + g * 4 + r;
                float v = S[mt][nt][r] * scale;
                if (j < 49 && i < 49) v += cb[i * 49 + j];
                S[mt][nt][r] = (j < 49) ? v : -INFINITY;
            }
        }
#pragma unroll
        for (int r = 0; r < 4; ++r) {
            float m = fmaxf(fmaxf(S[mt][0][r], S[mt][1][r]), fmaxf(S[mt][2][r], S[mt][3][r]));
            m = fmaxf(m, __shfl_xor(m, 1));
            m = fmaxf(m, __shfl_xor(m, 2));
            m = fmaxf(m, __shfl_xor(m, 4));
            m = fmaxf(m, __shfl_xor(m, 8));
            float s = 0.f;
#pragma unroll
            for (int nt = 0; nt < 4; ++nt) {
                float e = __expf(S[mt][nt][r] - m);
                S[mt][nt][r] = e;
                s += e;
            }
            s += __shfl_xor(s, 1);
            s += __shfl_xor(s, 2);
            s += __shfl_xor(s, 4);
            s += __shfl_xor(s, 8);
            inv[mt * 4 + r] = 1.f / s;
        }
    }

    __syncthreads();
#pragma unroll
    for (int mt = 0; mt < 4; ++mt)
#pragma unroll
        for (int nt = 0; nt < 4; ++nt)
#pragma unroll
            for (int r = 0; r < 4; ++r) {
                int i = mt * 16 + g * 4 + r, j = nt * 16 + c;
                W[(i * 64 + j) ^ ((i & 7) << 3)] = bf16bits(S[mt][nt][r]);
            }
    __syncthreads();

    f32x4 O[4][2];
#pragma unroll
    for (int mt = 0; mt < 4; ++mt)
#pragma unroll
        for (int dt = 0; dt < 2; ++dt) O[mt][dt] = (f32x4){0.f, 0.f, 0.f, 0.f};
#pragma unroll
    for (int ks = 0; ks < 2; ++ks) {
        bf16x8 pa[4], vb2[2];
#pragma unroll
        for (int mt = 0; mt < 4; ++mt) {
            int i = mt * 16 + c;
            pa[mt] = *(const bf16x8*)&W[(i * 64 + ks * 32 + g * 8) ^ ((i & 7) << 3)];
        }
#pragma unroll
        for (int dt = 0; dt < 2; ++dt) {
            int d = dt * 16 + c;
            vb2[dt] = *(const bf16x8*)&W[5120 + ((d * 64 + ks * 32 + g * 8) ^ ((d & 7) << 3))];
        }
#pragma unroll
        for (int mt = 0; mt < 4; ++mt)
#pragma unroll
            for (int dt = 0; dt < 2; ++dt)
                O[mt][dt] = __builtin_amdgcn_mfma_f32_16x16x32_bf16(pa[mt], vb2[dt],
                                                                    O[mt][dt], 0, 0, 0);
    }

#pragma unroll
    for (int mt = 0; mt < 4; ++mt)
#pragma unroll
        for (int r = 0; r < 4; ++r) {
            int i = mt * 16 + g * 4 + r;
            if (i < 49) {
#pragma unroll
                for (int dt = 0; dt < 2; ++dt) {
                    int d = dt * 16 + c;
                    out[((size_t)(b * 49 + i)) * 384 + h * 32 + d] =
                        __float2bfloat16(O[mt][dt][r] * inv[mt * 4 + r]);
                }
            }
        }
}

extern "C" void kernel_launch(void* const* d_in, const int* in_sizes, int n_in,
                              void* d_out, int out_size, void* d_ws, size_t ws_size,
                              hipStream_t stream) {
    (void)in_sizes; (void)n_in; (void)out_size; (void)ws_size;
    const float* x      = (const float*)d_in[0];
    const float* mask   = (const float*)d_in[1];
    const float* qkv_w  = (const float*)d_in[2];
    const float* qkv_b  = (const float*)d_in[3];
    const float* qa_w   = (const float*)d_in[4];
    const float* qb_w   = (const float*)d_in[5];
    const float* va_w   = (const float*)d_in[6];
    const float* vb_w   = (const float*)d_in[7];
    const float* rpb    = (const float*)d_in[8];
    const float* proj_w = (const float*)d_in[9];
    const float* proj_b = (const float*)d_in[10];

    char* ws = (char*)d_ws;
    // xb and attno share a region: xb dead after gemm1, attno written after.
    bf16* xb     = (bf16*)(ws);                    // 77,070,336 B
    bf16* attno  = (bf16*)(ws);                    // (same region, stream-ordered)
    bf16* wefft  = (bf16*)(ws + 77070336);         //    884,736 B
    bf16* projt  = (bf16*)(ws + 77955072);         //    294,912 B
    float* cbias = (float*)(ws + 78249984);        //  7,375,872 B
    bf16* qkv    = (bf16*)(ws + 85625856);         // 231,211,008 B (total ~317 MB)

    cvt_x_kernel<<<2048, 256, 0, stream>>>((const float4*)x, xb, 9633792);
    build_wefft_kernel<<<1728, 256, 0, stream>>>(qkv_w, qa_w, qb_w, va_w, vb_w, wefft);
    build_projt_kernel<<<576, 256, 0, stream>>>(proj_w, projt);
    build_cbias_kernel<<<7203, 256, 0, stream>>>(rpb, mask, cbias);
    // qkv[100352,1152] = xb[100352,384] @ wefft^T + qkv_b
    gemm_kernel<true><<<7056, 256, 0, stream>>>(xb, wefft, qkv_b, qkv, 1152, 384, 9, 7056);
    attn_kernel<<<6144, 256, 0, stream>>>(qkv, cbias, attno);
    // out[100352,384] = attno @ projt^T + proj_b  (fp32)
    gemm_kernel<false><<<2352, 256, 0, stream>>>(attno, projt, proj_b, d_out, 384, 384, 3, 2352);
}